// Round 1
// baseline (453.733 us; speedup 1.0000x reference)
//
#include <hip/hip_runtime.h>
#include <hip/hip_bf16.h>

#define N_NODES 8192
#define EMB 256
#define NHID 64
#define LOG2E 1.44269504088896340736f

typedef __attribute__((ext_vector_type(8))) short bf16x8;
typedef __attribute__((ext_vector_type(4))) float f32x4;

static __device__ __forceinline__ short f2bf(float f) {
  __hip_bfloat16 h = __float2bfloat16(f);  // round-to-nearest-even
  return *reinterpret_cast<short*>(&h);
}

// Kernel 1: h = input @ W. One wave per row (lane = d).
// Writes hT[d][row] (bf16, transposed so k2's B-fragments are contiguous),
// and s_src/s_dst pre-scaled by log2(e).
__global__ __launch_bounds__(256) void gat_k1(
    const float* __restrict__ in, const float* __restrict__ W,
    const float* __restrict__ a, short* __restrict__ hT,
    float* __restrict__ ssrc, float* __restrict__ sdst) {
  int wave = threadIdx.x >> 6, lane = threadIdx.x & 63;
  int row = blockIdx.x * 4 + wave;
  int d = lane;
  const float4* in4 = reinterpret_cast<const float4*>(in + (size_t)row * EMB);
  float acc = 0.f;
#pragma unroll 4
  for (int k4 = 0; k4 < EMB / 4; ++k4) {
    float4 x = in4[k4];
    int k = k4 * 4;
    acc = fmaf(x.x, W[(k + 0) * NHID + d], acc);
    acc = fmaf(x.y, W[(k + 1) * NHID + d], acc);
    acc = fmaf(x.z, W[(k + 2) * NHID + d], acc);
    acc = fmaf(x.w, W[(k + 3) * NHID + d], acc);
  }
  hT[(size_t)d * N_NODES + row] = f2bf(acc);
  float p1 = acc * a[d];
  float p2 = acc * a[NHID + d];
#pragma unroll
  for (int off = 32; off > 0; off >>= 1) {
    p1 += __shfl_xor(p1, off);
    p2 += __shfl_xor(p2, off);
  }
  if (lane == 0) {
    ssrc[row] = p1 * LOG2E;
    sdst[row] = p2 * LOG2E;
  }
}

// Kernel 2: fused masked-exp + P@h via bf16 MFMA, single pass over adj.
// Grid = (8192/64 row-blocks) x nsplit column splits. 4 waves/block, each wave
// owns 16 rows. A-fragment (P) computed in registers; B from hT (global,
// L2-resident). Unnormalized: also accumulates row sums Z. No LDS.
__global__ __launch_bounds__(256, 4) void gat_k2(
    const int* __restrict__ adj, const short* __restrict__ hT,
    const float* __restrict__ ssrc, const float* __restrict__ sdst,
    float* __restrict__ pacc, float* __restrict__ pz,
    int nsplit, int colsPer) {
  int rb = blockIdx.x / nsplit;
  int split = blockIdx.x % nsplit;
  int wv = threadIdx.x >> 6, lane = threadIdx.x & 63;
  int lrow = lane & 15, kg = lane >> 4;
  int r0 = rb * 64 + wv * 16;
  int row = r0 + lrow;
  float s_i = ssrc[row];
  const int* adjr = adj + (size_t)row * N_NODES;
  const short* hrow0 = hT + (size_t)(0 * 16 + lrow) * N_NODES;
  const short* hrow1 = hT + (size_t)(1 * 16 + lrow) * N_NODES;
  const short* hrow2 = hT + (size_t)(2 * 16 + lrow) * N_NODES;
  const short* hrow3 = hT + (size_t)(3 * 16 + lrow) * N_NODES;
  f32x4 acc0 = {0.f, 0.f, 0.f, 0.f};
  f32x4 acc1 = acc0, acc2 = acc0, acc3 = acc0;
  float zacc = 0.f;
  int jbase = split * colsPer + kg * 8;  // this lane's k-offset
  int nkt = colsPer >> 5;                // 32 cols per K-tile

  // software prefetch (1 deep) of the HBM-latency-critical adj stream
  int4 aj0 = *reinterpret_cast<const int4*>(adjr + jbase);
  int4 aj1 = *reinterpret_cast<const int4*>(adjr + jbase + 4);
  float4 t0 = *reinterpret_cast<const float4*>(sdst + jbase);
  float4 t1 = *reinterpret_cast<const float4*>(sdst + jbase + 4);

  for (int kt = 0; kt < nkt; ++kt) {
    int jb = jbase + kt * 32;
    int jn = (kt + 1 < nkt) ? (jb + 32) : jbase;
    int4 naj0 = *reinterpret_cast<const int4*>(adjr + jn);
    int4 naj1 = *reinterpret_cast<const int4*>(adjr + jn + 4);
    float4 nt0 = *reinterpret_cast<const float4*>(sdst + jn);
    float4 nt1 = *reinterpret_cast<const float4*>(sdst + jn + 4);

    float tv[8] = {t0.x, t0.y, t0.z, t0.w, t1.x, t1.y, t1.z, t1.w};
    int av[8] = {aj0.x, aj0.y, aj0.z, aj0.w, aj1.x, aj1.y, aj1.z, aj1.w};
    bf16x8 af;
#pragma unroll
    for (int e = 0; e < 8; ++e) {
      float x = s_i + tv[e];                   // log2-domain score
      float lk = fmaxf(x, 0.2f * x);           // leakyrelu (alpha<1)
      float ev = __builtin_amdgcn_exp2f(lk);   // exp(leaky(s+t))
      float w = (av[e] != 0) ? ev : 0.f;       // mask
      zacc += w;
      af[e] = f2bf(w);
    }
    bf16x8 b0 = *reinterpret_cast<const bf16x8*>(hrow0 + jb);
    bf16x8 b1 = *reinterpret_cast<const bf16x8*>(hrow1 + jb);
    bf16x8 b2 = *reinterpret_cast<const bf16x8*>(hrow2 + jb);
    bf16x8 b3 = *reinterpret_cast<const bf16x8*>(hrow3 + jb);
    acc0 = __builtin_amdgcn_mfma_f32_16x16x32_bf16(af, b0, acc0, 0, 0, 0);
    acc1 = __builtin_amdgcn_mfma_f32_16x16x32_bf16(af, b1, acc1, 0, 0, 0);
    acc2 = __builtin_amdgcn_mfma_f32_16x16x32_bf16(af, b2, acc2, 0, 0, 0);
    acc3 = __builtin_amdgcn_mfma_f32_16x16x32_bf16(af, b3, acc3, 0, 0, 0);

    aj0 = naj0; aj1 = naj1; t0 = nt0; t1 = nt1;
  }

  // Z: A-layout row = lane&15; full sum over lanes {r, r+16, r+32, r+48}
  float z = zacc;
  z += __shfl_xor(z, 16);
  z += __shfl_xor(z, 32);
  if (lane < 16) pz[(size_t)split * N_NODES + r0 + lane] = z;

  // C/D layout: row = (lane>>4)*4 + reg, col = lane&15
  float* pa = pacc + (size_t)split * (N_NODES * NHID);
#pragma unroll
  for (int reg = 0; reg < 4; ++reg) {
    int orow = r0 + kg * 4 + reg;
    pa[(size_t)orow * NHID + 0 * 16 + lrow] = acc0[reg];
    pa[(size_t)orow * NHID + 1 * 16 + lrow] = acc1[reg];
    pa[(size_t)orow * NHID + 2 * 16 + lrow] = acc2[reg];
    pa[(size_t)orow * NHID + 3 * 16 + lrow] = acc3[reg];
  }
}

// Kernel 3: combine split partials and normalize.
__global__ __launch_bounds__(256) void gat_k3(
    const float* __restrict__ pacc, const float* __restrict__ pz,
    float* __restrict__ out, int nsplit) {
  int idx = blockIdx.x * 256 + threadIdx.x;
  int row = idx >> 6;
  float num = 0.f, den = 0.f;
  for (int s = 0; s < nsplit; ++s) {
    num += pacc[(size_t)s * (N_NODES * NHID) + idx];
    den += pz[(size_t)s * N_NODES + row];
  }
  out[idx] = num / den;
}

extern "C" void kernel_launch(void* const* d_in, const int* in_sizes, int n_in,
                              void* d_out, int out_size, void* d_ws, size_t ws_size,
                              hipStream_t stream) {
  (void)in_sizes; (void)n_in; (void)out_size;
  const float* in = (const float*)d_in[0];
  const int* adj = (const int*)d_in[1];
  const float* W = (const float*)d_in[2];
  const float* a = (const float*)d_in[3];
  float* out = (float*)d_out;

  // ws: hT (1 MB) | ssrc (32K) | sdst (32K) | pz (S*32K) | pacc (S*2 MB)
  int S = 8;
  while (S > 1 && (size_t)1114112 + (size_t)S * 2129920 > ws_size) S >>= 1;
  int colsPer = N_NODES / S;

  char* w = (char*)d_ws;
  short* hT = (short*)w;
  float* ssrc = (float*)(w + (1u << 20));
  float* sdst = ssrc + N_NODES;
  float* pz = sdst + N_NODES;
  float* pacc = pz + (size_t)S * N_NODES;

  gat_k1<<<N_NODES / 4, 256, 0, stream>>>(in, W, a, hT, ssrc, sdst);
  gat_k2<<<(N_NODES / 64) * S, 256, 0, stream>>>(adj, hT, ssrc, sdst, pacc, pz,
                                                 S, colsPer);
  gat_k3<<<(N_NODES * NHID) / 256, 256, 0, stream>>>(pacc, pz, out, S);
}

// Round 2
// 447.379 us; speedup vs baseline: 1.0142x; 1.0142x over previous
//
#include <hip/hip_runtime.h>
#include <hip/hip_bf16.h>

#define N_NODES 8192
#define EMB 256
#define NHID 64
#define LOG2E 1.44269504088896340736f

typedef __attribute__((ext_vector_type(8))) short bf16x8;
typedef __attribute__((ext_vector_type(4))) float f32x4;

static __device__ __forceinline__ short f2bf(float f) {
  __hip_bfloat16 h = __float2bfloat16(f);  // round-to-nearest-even
  return *reinterpret_cast<short*>(&h);
}

// fast bf16 round (half-up in magnitude) — valid for finite values; used on
// the nonnegative attention weights where ties-away vs ties-even is noise.
static __device__ __forceinline__ short f2bf_fast(float f) {
  unsigned u = __builtin_bit_cast(unsigned, f);
  return (short)((u + 0x8000u) >> 16);
}

// Kernel 1: h = input @ W. One wave per row (lane = d).
// Writes hT[d][row] (bf16, transposed so k2's B-fragments are contiguous),
// and s_src/s_dst pre-scaled by log2(e).
__global__ __launch_bounds__(256) void gat_k1(
    const float* __restrict__ in, const float* __restrict__ W,
    const float* __restrict__ a, short* __restrict__ hT,
    float* __restrict__ ssrc, float* __restrict__ sdst) {
  int wave = threadIdx.x >> 6, lane = threadIdx.x & 63;
  int row = blockIdx.x * 4 + wave;
  int d = lane;
  const float4* in4 = reinterpret_cast<const float4*>(in + (size_t)row * EMB);
  float acc = 0.f;
#pragma unroll 4
  for (int k4 = 0; k4 < EMB / 4; ++k4) {
    float4 x = in4[k4];
    int k = k4 * 4;
    acc = fmaf(x.x, W[(k + 0) * NHID + d], acc);
    acc = fmaf(x.y, W[(k + 1) * NHID + d], acc);
    acc = fmaf(x.z, W[(k + 2) * NHID + d], acc);
    acc = fmaf(x.w, W[(k + 3) * NHID + d], acc);
  }
  hT[(size_t)d * N_NODES + row] = f2bf(acc);
  float p1 = acc * a[d];
  float p2 = acc * a[NHID + d];
#pragma unroll
  for (int off = 32; off > 0; off >>= 1) {
    p1 += __shfl_xor(p1, off);
    p2 += __shfl_xor(p2, off);
  }
  if (lane == 0) {
    ssrc[row] = p1 * LOG2E;
    sdst[row] = p2 * LOG2E;
  }
}

// Kernel 2: fused masked-exp + P@h via bf16 MFMA, single pass over adj.
// Grid = (8192/64 row-blocks) x nsplit column splits. 4 waves/block, each wave
// owns 16 rows. A-fragment (P) computed in registers; B from hT (global,
// L2-resident). Unnormalized: also accumulates row sums Z. No LDS.
// All streams (adj, sdst, hT) are 1-K-tile software-prefetched.
__global__ __launch_bounds__(256, 4) void gat_k2(
    const int* __restrict__ adj, const short* __restrict__ hT,
    const float* __restrict__ ssrc, const float* __restrict__ sdst,
    float* __restrict__ pacc, float* __restrict__ pz,
    int nsplit, int colsPer) {
  int rb = blockIdx.x / nsplit;
  int split = blockIdx.x % nsplit;
  int wv = threadIdx.x >> 6, lane = threadIdx.x & 63;
  int lrow = lane & 15, kg = lane >> 4;
  int r0 = rb * 64 + wv * 16;
  int row = r0 + lrow;
  float s_i = ssrc[row];
  const int* adjr = adj + (size_t)row * N_NODES;
  const short* hrow0 = hT + (size_t)(0 * 16 + lrow) * N_NODES;
  const short* hrow1 = hT + (size_t)(1 * 16 + lrow) * N_NODES;
  const short* hrow2 = hT + (size_t)(2 * 16 + lrow) * N_NODES;
  const short* hrow3 = hT + (size_t)(3 * 16 + lrow) * N_NODES;
  f32x4 acc0 = {0.f, 0.f, 0.f, 0.f};
  f32x4 acc1 = acc0, acc2 = acc0, acc3 = acc0;
  float zacc = 0.f;
  int jbase = split * colsPer + kg * 8;  // this lane's k-offset
  int nkt = colsPer >> 5;                // 32 cols per K-tile

  // 1-deep software prefetch of ALL per-tile streams
  int4 aj0 = *reinterpret_cast<const int4*>(adjr + jbase);
  int4 aj1 = *reinterpret_cast<const int4*>(adjr + jbase + 4);
  float4 t0 = *reinterpret_cast<const float4*>(sdst + jbase);
  float4 t1 = *reinterpret_cast<const float4*>(sdst + jbase + 4);
  bf16x8 b0 = *reinterpret_cast<const bf16x8*>(hrow0 + jbase);
  bf16x8 b1 = *reinterpret_cast<const bf16x8*>(hrow1 + jbase);
  bf16x8 b2 = *reinterpret_cast<const bf16x8*>(hrow2 + jbase);
  bf16x8 b3 = *reinterpret_cast<const bf16x8*>(hrow3 + jbase);

  for (int kt = 0; kt < nkt; ++kt) {
    int jn = (kt + 1 < nkt) ? (jbase + (kt + 1) * 32) : jbase;
    int4 naj0 = *reinterpret_cast<const int4*>(adjr + jn);
    int4 naj1 = *reinterpret_cast<const int4*>(adjr + jn + 4);
    float4 nt0 = *reinterpret_cast<const float4*>(sdst + jn);
    float4 nt1 = *reinterpret_cast<const float4*>(sdst + jn + 4);
    bf16x8 nb0 = *reinterpret_cast<const bf16x8*>(hrow0 + jn);
    bf16x8 nb1 = *reinterpret_cast<const bf16x8*>(hrow1 + jn);
    bf16x8 nb2 = *reinterpret_cast<const bf16x8*>(hrow2 + jn);
    bf16x8 nb3 = *reinterpret_cast<const bf16x8*>(hrow3 + jn);

    float tv[8] = {t0.x, t0.y, t0.z, t0.w, t1.x, t1.y, t1.z, t1.w};
    int av[8] = {aj0.x, aj0.y, aj0.z, aj0.w, aj1.x, aj1.y, aj1.z, aj1.w};
    bf16x8 af;
#pragma unroll
    for (int e = 0; e < 8; ++e) {
      float x = s_i + tv[e];                   // log2-domain score
      float lk = fmaxf(x, 0.2f * x);           // leakyrelu (alpha<1)
      float ev = __builtin_amdgcn_exp2f(lk);   // exp(leaky(s+t))
      float w = (av[e] != 0) ? ev : 0.f;       // mask
      zacc += w;
      af[e] = f2bf_fast(w);
    }
    acc0 = __builtin_amdgcn_mfma_f32_16x16x32_bf16(af, b0, acc0, 0, 0, 0);
    acc1 = __builtin_amdgcn_mfma_f32_16x16x32_bf16(af, b1, acc1, 0, 0, 0);
    acc2 = __builtin_amdgcn_mfma_f32_16x16x32_bf16(af, b2, acc2, 0, 0, 0);
    acc3 = __builtin_amdgcn_mfma_f32_16x16x32_bf16(af, b3, acc3, 0, 0, 0);

    aj0 = naj0; aj1 = naj1; t0 = nt0; t1 = nt1;
    b0 = nb0; b1 = nb1; b2 = nb2; b3 = nb3;
  }

  // Z: A-layout row = lane&15; full sum over lanes {r, r+16, r+32, r+48}
  float z = zacc;
  z += __shfl_xor(z, 16);
  z += __shfl_xor(z, 32);
  if (lane < 16) pz[(size_t)split * N_NODES + r0 + lane] = z;

  // C/D layout: row = (lane>>4)*4 + reg, col = lane&15
  float* pa = pacc + (size_t)split * (N_NODES * NHID);
#pragma unroll
  for (int reg = 0; reg < 4; ++reg) {
    int orow = r0 + kg * 4 + reg;
    pa[(size_t)orow * NHID + 0 * 16 + lrow] = acc0[reg];
    pa[(size_t)orow * NHID + 1 * 16 + lrow] = acc1[reg];
    pa[(size_t)orow * NHID + 2 * 16 + lrow] = acc2[reg];
    pa[(size_t)orow * NHID + 3 * 16 + lrow] = acc3[reg];
  }
}

// Kernel 3: combine split partials and normalize.
__global__ __launch_bounds__(256) void gat_k3(
    const float* __restrict__ pacc, const float* __restrict__ pz,
    float* __restrict__ out, int nsplit) {
  int idx = blockIdx.x * 256 + threadIdx.x;
  int row = idx >> 6;
  float num = 0.f, den = 0.f;
  for (int s = 0; s < nsplit; ++s) {
    num += pacc[(size_t)s * (N_NODES * NHID) + idx];
    den += pz[(size_t)s * N_NODES + row];
  }
  out[idx] = num / den;
}

extern "C" void kernel_launch(void* const* d_in, const int* in_sizes, int n_in,
                              void* d_out, int out_size, void* d_ws, size_t ws_size,
                              hipStream_t stream) {
  (void)in_sizes; (void)n_in; (void)out_size;
  const float* in = (const float*)d_in[0];
  const int* adj = (const int*)d_in[1];
  const float* W = (const float*)d_in[2];
  const float* a = (const float*)d_in[3];
  float* out = (float*)d_out;

  // ws: hT (1 MB) | ssrc (32K) | sdst (32K) | pz (S*32K) | pacc (S*2 MB)
  int S = 8;
  while (S > 1 && (size_t)1114112 + (size_t)S * 2129920 > ws_size) S >>= 1;
  int colsPer = N_NODES / S;

  char* w = (char*)d_ws;
  short* hT = (short*)w;
  float* ssrc = (float*)(w + (1u << 20));
  float* sdst = ssrc + N_NODES;
  float* pz = sdst + N_NODES;
  float* pacc = pz + (size_t)S * N_NODES;

  gat_k1<<<N_NODES / 4, 256, 0, stream>>>(in, W, a, hT, ssrc, sdst);
  gat_k2<<<(N_NODES / 64) * S, 256, 0, stream>>>(adj, hT, ssrc, sdst, pacc, pz,
                                                 S, colsPer);
  gat_k3<<<(N_NODES * NHID) / 256, 256, 0, stream>>>(pacc, pz, out, S);
}